// Round 9
// baseline (486.999 us; speedup 1.0000x reference)
//
#include <hip/hip_runtime.h>
#include <hip/hip_bf16.h>

// Problem sizes (fixed by reference setup_inputs):
//   B=16, N_LOG=512, N_PHYS(Q)=2048, E=2048
#define BATCH 16
#define NLOG 512
#define Q 2048
#define NEDGE 2048
#define M_TOT (BATCH * NLOG)   // 8192 GEMM rows
#define KB 2048                // K bytes per row (fp8, 1 B/elem)
#define GEMM_BLOCKS 256        // 32 x 8

typedef float f32x2 __attribute__((ext_vector_type(2)));
typedef float f32x4 __attribute__((ext_vector_type(4)));
typedef int i32x4 __attribute__((ext_vector_type(4)));
typedef int i32x8 __attribute__((ext_vector_type(8)));

// one OCP e4m3 byte -> f32 via HW packed convert (low element).
__device__ __forceinline__ float fp8_to_f32(unsigned char v) {
    f32x2 p = __builtin_amdgcn_cvt_pk_f32_fp8((int)v, false);
    return p[0];
}

// ---------------------------------------------------------------------------
// K1 (fused prep): blocks [0,8192) convert P fp32 -> P8 (e4m3, 8 elem/thr,
// 8B packed stores); blocks [8192,12288) build A8[p][q] = (d_hw[p][q]==1)
// as e4m3 bytes (1.0 = 0x38) -- UNtransposed now (the M-formulation's GEMM
// needs B-rows over p with k=q, i.e. plain row-major A). Straight stream:
// int4 in, packed u32 out. Block 0 zeroes adj/wsum + the done counter.
__global__ __launch_bounds__(256) void prep(const float* __restrict__ P,
                                            unsigned char* __restrict__ P8,
                                            const int* __restrict__ d_hw,
                                            unsigned char* __restrict__ A8,
                                            float* __restrict__ adj,
                                            float* __restrict__ wsum,
                                            unsigned* __restrict__ counter) {
    int bid = blockIdx.x;
    if (bid == 0) {
        if (threadIdx.x == 0) *counter = 0u;
        if (threadIdx.x < BATCH) { adj[threadIdx.x] = 0.f; wsum[threadIdx.x] = 0.f; }
    }
    if (bid < 8192) {
        int i = (bid * 256 + threadIdx.x) * 8;
        float4 v0 = *(const float4*)(P + i);
        float4 v1 = *(const float4*)(P + i + 4);
        int lo = 0, hi = 0;
        lo = __builtin_amdgcn_cvt_pk_fp8_f32(v0.x, v0.y, lo, false);
        lo = __builtin_amdgcn_cvt_pk_fp8_f32(v0.z, v0.w, lo, true);
        hi = __builtin_amdgcn_cvt_pk_fp8_f32(v1.x, v1.y, hi, false);
        hi = __builtin_amdgcn_cvt_pk_fp8_f32(v1.z, v1.w, hi, true);
        int2 st; st.x = lo; st.y = hi;
        *(int2*)(P8 + i) = st;
    } else {
        int idx = ((bid - 8192) * 256 + threadIdx.x) * 4;   // element index
        int4 v = *(const int4*)(d_hw + idx);
        unsigned pk = (v.x == 1 ? 0x38u : 0u)
                    | (v.y == 1 ? 0x38u : 0u) << 8
                    | (v.z == 1 ? 0x38u : 0u) << 16
                    | (v.w == 1 ? 0x38u : 0u) << 24;
        *(unsigned*)(A8 + idx) = pk;
    }
}

// ---------------------------------------------------------------------------
// K2 (m_build): M[b][i][q] = sum_{e: src_e=i} w_e * P[b][dst_e][q], stored
// e4m3 (values ~O(1..30) << 448 e4m3 max; no scale needed). Grid 512 =
// (batch, 64-col q-slice): LDS tile Mlds[512][64] f32 = 128 KB (1 blk/CU).
// Per edge (loop-uniform metadata -> scalar loads): lane l accumulates
// col l via LDS atomicAdd -- 64 lanes hit banks l&31 = 2 lanes/bank (free,
// m136). Wave's P8 read = 64 consecutive bytes (1 transaction), dst rows
// ~4x reused -> L2-hot. Edge traffic: 512 blk x 128 KB = 64 MB logical,
// mostly cached. qs==0 blocks also compute wsum[b]: w_e is lane-uniform,
// so each wave's 256-edge partial needs NO reduce -- 8 global atomicAdds.
__global__ __launch_bounds__(512) void m_build(const unsigned char* __restrict__ P8,
                                               const int* __restrict__ esrc,
                                               const int* __restrict__ edst,
                                               const float* __restrict__ ew,
                                               unsigned char* __restrict__ M8,
                                               float* __restrict__ wsum) {
    const int b  = blockIdx.x >> 5;
    const int qs = blockIdx.x & 31;
    const int q0 = qs * 64;
    const int t = threadIdx.x;
    const int w = t >> 6;
    const int lane = t & 63;

    __shared__ float Mlds[NLOG][64];   // 128 KB exactly

    // zero: thread t covers rows t>>3 stepped by 64, 8 cols each.
    #pragma unroll
    for (int pass = 0; pass < 8; pass++) {
        float* mp = &Mlds[pass * 64 + (t >> 3)][(t & 7) * 8];
        #pragma unroll
        for (int c = 0; c < 8; c++) mp[c] = 0.f;
    }
    __syncthreads();

    const unsigned char* Pb = P8 + (size_t)b * NLOG * Q + q0 + lane;
    const int ebase = b * NEDGE + w * 256;
    float wacc = 0.f;   // lane-uniform
    #pragma unroll 8
    for (int e = 0; e < 256; e++) {
        int dst = edst[ebase + e];                     // uniform -> s_load
        int src = esrc[ebase + e];
        float we = ew[ebase + e];
        float v = fp8_to_f32(Pb[(size_t)dst * Q]);
        atomicAdd(&Mlds[src][lane], we * v);
        wacc += we;
    }
    if (qs == 0 && lane == 0) atomicAdd(&wsum[b], wacc);
    __syncthreads();

    // writeback: thread t -> row (t>>3)+64*pass, cols (t&7)*8 .. +8 (8B
    // per thread; 8 consecutive threads = 64 contiguous bytes).
    #pragma unroll
    for (int pass = 0; pass < 8; pass++) {
        int row = pass * 64 + (t >> 3);
        const float* mp = &Mlds[row][(t & 7) * 8];
        int d0 = 0, d1 = 0;
        d0 = __builtin_amdgcn_cvt_pk_fp8_f32(mp[0], mp[1], d0, false);
        d0 = __builtin_amdgcn_cvt_pk_fp8_f32(mp[2], mp[3], d0, true);
        d1 = __builtin_amdgcn_cvt_pk_fp8_f32(mp[4], mp[5], d1, false);
        d1 = __builtin_amdgcn_cvt_pk_fp8_f32(mp[6], mp[7], d1, true);
        int2 st; st.x = d0; st.y = d1;
        *(int2*)(M8 + (size_t)(b * NLOG + row) * Q + q0 + (t & 7) * 8) = st;
    }
}

// ---------------------------------------------------------------------------
// K3: fused GEMM+loss  R[i,p] = sum_q M8[i,q] * A8[p,q]; then
// s_b += sum_tile R[i,p] * P8[i,p] (each P8 byte read exactly once across
// the grid), atomicAdd per block, counter-gated finalize in last block.
// Identity: s_b = sum_e w_e * (P[src]A)·P[dst]  -- replaces the ~29us
// latency-bound edge gather entirely; no PA8 write, no scale factors.
// Schedule = R7's 4-phase role-split per K-tile: {ds_read 1/4 frags ||
// 2-3 staging loads for next K-tile -> RAW s_barrier -> setprio(1) ->
// 8 MFMAs -> setprio(0) -> raw barrier}; one vmcnt(0) per K-tile boundary.
// 256x256 C-tile, 8 waves (2M x 4N), LDS 2x(32K+32K)=128KB, 1 block/CU.
// Chunk swizzle: rows are 128B = 32 banks; phys chunk = logical ^ (row&7).
#define MF(af, bf, accv) __builtin_amdgcn_mfma_scale_f32_16x16x128_f8f6f4( \
    (af), (bf), (accv), 0, 0, 0, 127, 0, 127)

#define READ_FRAG(buf, rowbase) __extension__({                                \
    const int _b = ((rowbase) + lane16) << 7;                                  \
    i32x4 _lo = *(const i32x4*)((buf) + _b + c0);                              \
    i32x4 _hi = *(const i32x4*)((buf) + _b + c1);                              \
    __builtin_shufflevector(_lo, _hi, 0, 1, 2, 3, 4, 5, 6, 7); })

#define SA(dstbuf, c, kk0)                                                     \
    __builtin_amdgcn_global_load_lds(                                          \
        (const __attribute__((address_space(1))) void*)(Mm +                   \
            (size_t)(m0 + (c) * 64 + s_row) * KB + (kk0) + s_off),             \
        (__attribute__((address_space(3))) void*)((dstbuf) + (c) * 8192 + t * 16), \
        16, 0, 0)
#define SB(dstbuf, c, kk0)                                                     \
    __builtin_amdgcn_global_load_lds(                                          \
        (const __attribute__((address_space(1))) void*)(Aa +                   \
            (size_t)(n0 + (c) * 64 + s_row) * KB + (kk0) + s_off),             \
        (__attribute__((address_space(3))) void*)((dstbuf) + (c) * 8192 + t * 16), \
        16, 0, 0)

__global__ __launch_bounds__(512, 2) void gemm_fused(const unsigned char* __restrict__ Mm,
                                                     const unsigned char* __restrict__ Aa,
                                                     const unsigned char* __restrict__ P8,
                                                     float* __restrict__ adj,
                                                     const float* __restrict__ wsum,
                                                     unsigned* __restrict__ counter,
                                                     float* __restrict__ out) {
    __shared__ unsigned char As[2][32768];  // 2 x (256 x 128)  (M-tiles)
    __shared__ unsigned char Bs[2][32768];  // 2 x (256 x 128)  (A-tiles)
    __shared__ float rs[8];

    const int t = threadIdx.x;
    const int w = t >> 6;                   // 0..7
    const int wr = w >> 2, wc = w & 3;      // 2M x 4N wave grid
    const int l = t & 63;
    const int quad = l >> 4;
    const int lane16 = l & 15;

    const int m0 = blockIdx.x * 256;
    const int n0 = blockIdx.y * 256;
    const int b = blockIdx.x >> 1;          // 512 rows per batch

    const int s_row = t >> 3;                            // 0..63
    const int s_off = (((t & 7) ^ (s_row & 7)) << 4);    // swizzled src byte

    const int r7 = lane16 & 7;
    const int c0 = ((2 * quad) ^ r7) << 4;
    const int c1 = ((2 * quad + 1) ^ r7) << 4;

    f32x4 acc[8][4] = {};

    // prologue: stage K-tile 0 into buffer 0, full drain once.
    {
        SA(As[0], 0, 0); SA(As[0], 1, 0); SA(As[0], 2, 0); SA(As[0], 3, 0);
        SB(Bs[0], 0, 0); SB(Bs[0], 1, 0); SB(Bs[0], 2, 0); SB(Bs[0], 3, 0);
    }
    __syncthreads();

    for (int kt = 0; kt < 16; ++kt) {
        const unsigned char* as = As[kt & 1];
        const unsigned char* bs = Bs[kt & 1];
        unsigned char* an = As[(kt + 1) & 1];
        unsigned char* bn = Bs[(kt + 1) & 1];
        const int kn = (kt + 1) * 128;
        const bool st = (kt < 15);

        // ---- phase 0: B0-3 + A0-1 reads; stage A-calls 0-2.
        i32x8 bf0 = READ_FRAG(bs, wc * 64 + 0);
        i32x8 bf1 = READ_FRAG(bs, wc * 64 + 16);
        i32x8 bf2 = READ_FRAG(bs, wc * 64 + 32);
        i32x8 bf3 = READ_FRAG(bs, wc * 64 + 48);
        i32x8 af0 = READ_FRAG(as, wr * 128 + 0);
        i32x8 af1 = READ_FRAG(as, wr * 128 + 16);
        if (st) { SA(an, 0, kn); SA(an, 1, kn); SA(an, 2, kn); }
        __builtin_amdgcn_s_barrier();
        __builtin_amdgcn_s_setprio(1);
        acc[0][0] = MF(af0, bf0, acc[0][0]); acc[0][1] = MF(af0, bf1, acc[0][1]);
        acc[0][2] = MF(af0, bf2, acc[0][2]); acc[0][3] = MF(af0, bf3, acc[0][3]);
        acc[1][0] = MF(af1, bf0, acc[1][0]); acc[1][1] = MF(af1, bf1, acc[1][1]);
        acc[1][2] = MF(af1, bf2, acc[1][2]); acc[1][3] = MF(af1, bf3, acc[1][3]);
        __builtin_amdgcn_s_setprio(0);
        __builtin_amdgcn_s_barrier();

        // ---- phase 1: A2-3 reads; stage A-call 3 + B-calls 0-1.
        i32x8 af2 = READ_FRAG(as, wr * 128 + 32);
        i32x8 af3 = READ_FRAG(as, wr * 128 + 48);
        if (st) { SA(an, 3, kn); SB(bn, 0, kn); SB(bn, 1, kn); }
        __builtin_amdgcn_s_barrier();
        __builtin_amdgcn_s_setprio(1);
        acc[2][0] = MF(af2, bf0, acc[2][0]); acc[2][1] = MF(af2, bf1, acc[2][1]);
        acc[2][2] = MF(af2, bf2, acc[2][2]); acc[2][3] = MF(af2, bf3, acc[2][3]);
        acc[3][0] = MF(af3, bf0, acc[3][0]); acc[3][1] = MF(af3, bf1, acc[3][1]);
        acc[3][2] = MF(af3, bf2, acc[3][2]); acc[3][3] = MF(af3, bf3, acc[3][3]);
        __builtin_amdgcn_s_setprio(0);
        __builtin_amdgcn_s_barrier();

        // ---- phase 2: A4-5 reads; stage B-calls 2-3 (staging done here).
        i32x8 af4 = READ_FRAG(as, wr * 128 + 64);
        i32x8 af5 = READ_FRAG(as, wr * 128 + 80);
        if (st) { SB(bn, 2, kn); SB(bn, 3, kn); }
        __builtin_amdgcn_s_barrier();
        __builtin_amdgcn_s_setprio(1);
        acc[4][0] = MF(af4, bf0, acc[4][0]); acc[4][1] = MF(af4, bf1, acc[4][1]);
        acc[4][2] = MF(af4, bf2, acc[4][2]); acc[4][3] = MF(af4, bf3, acc[4][3]);
        acc[5][0] = MF(af5, bf0, acc[5][0]); acc[5][1] = MF(af5, bf1, acc[5][1]);
        acc[5][2] = MF(af5, bf2, acc[5][2]); acc[5][3] = MF(af5, bf3, acc[5][3]);
        __builtin_amdgcn_s_setprio(0);
        __builtin_amdgcn_s_barrier();

        // ---- phase 3: A6-7 reads; no staging; boundary vmcnt wait.
        i32x8 af6 = READ_FRAG(as, wr * 128 + 96);
        i32x8 af7 = READ_FRAG(as, wr * 128 + 112);
        __builtin_amdgcn_s_barrier();
        __builtin_amdgcn_s_setprio(1);
        acc[6][0] = MF(af6, bf0, acc[6][0]); acc[6][1] = MF(af6, bf1, acc[6][1]);
        acc[6][2] = MF(af6, bf2, acc[6][2]); acc[6][3] = MF(af6, bf3, acc[6][3]);
        acc[7][0] = MF(af7, bf0, acc[7][0]); acc[7][1] = MF(af7, bf1, acc[7][1]);
        acc[7][2] = MF(af7, bf2, acc[7][2]); acc[7][3] = MF(af7, bf3, acc[7][3]);
        __builtin_amdgcn_s_setprio(0);
        asm volatile("s_waitcnt vmcnt(0)" ::: "memory");
        __builtin_amdgcn_s_barrier();
    }

    // epilogue: s = sum over this block's tile of R[row,col] * P[row,col].
    // C/D layout (shape-determined): col=lane&15, row=quad*4+reg.
    float s = 0.f;
    #pragma unroll
    for (int i = 0; i < 8; i++) {
        #pragma unroll
        for (int j = 0; j < 4; j++) {
            #pragma unroll
            for (int r = 0; r < 4; r++) {
                int row = m0 + wr * 128 + i * 16 + quad * 4 + r;
                int col = n0 + wc * 64 + j * 16 + lane16;
                s += acc[i][j][r] * fp8_to_f32(P8[(size_t)row * Q + col]);
            }
        }
    }
    #pragma unroll
    for (int o = 32; o > 0; o >>= 1) s += __shfl_xor(s, o);
    if (l == 0) rs[w] = s;
    __syncthreads();

    if (t == 0) {
        float a = 0.f;
        #pragma unroll
        for (int i = 0; i < 8; i++) a += rs[i];
        atomicAdd(&adj[b], a);
        __threadfence();
        if (atomicAdd(counter, 1u) == GEMM_BLOCKS - 1) {
            __threadfence();
            float sm = 0.f;
            #pragma unroll
            for (int bb = 0; bb < BATCH; bb++) {
                float av = atomicAdd(&adj[bb], 0.0f);   // device-scope read
                float wv = atomicAdd((float*)&wsum[bb], 0.0f);
                sm += av / fmaxf(wv, 1e-8f);
            }
            out[0] = -sm / (float)BATCH;
        }
    }
}

// ---------------------------------------------------------------------------
extern "C" void kernel_launch(void* const* d_in, const int* in_sizes, int n_in,
                              void* d_out, int out_size, void* d_ws, size_t ws_size,
                              hipStream_t stream) {
    const float* P    = (const float*)d_in[0];
    const int* d_hw   = (const int*)d_in[1];
    const int* esrc   = (const int*)d_in[2];
    const int* edst   = (const int*)d_in[3];
    const float* ew   = (const float*)d_in[4];
    float* out        = (float*)d_out;

    char* ws = (char*)d_ws;
    // workspace layout (bytes), total ~37.7 MB:
    //   P8  : e4m3 [B*N*Q]  = 16,777,216   [0, 16.8M)
    //   A8  : e4m3 [Q*Q]    =  4,194,304   [16.8M, 21.0M)   (row-major, no T)
    //   M8  : e4m3 [B*N*Q]  = 16,777,216   [21.0M, 37.7M)
    //   adj/wsum/counter at 37.7M
    unsigned char* P8  = (unsigned char*)ws;
    unsigned char* A8  = (unsigned char*)(ws + 16777216);
    unsigned char* M8  = (unsigned char*)(ws + 20971520);
    float* adj         = (float*)(ws + 37748736);
    float* wsum        = (float*)(ws + 37748736 + 64);
    unsigned* counter  = (unsigned*)(ws + 37748736 + 128);

    prep<<<8192 + 4096, 256, 0, stream>>>(P, P8, d_hw, A8, adj, wsum, counter);
    m_build<<<512, 512, 0, stream>>>(P8, esrc, edst, ew, M8, wsum);
    gemm_fused<<<dim3(M_TOT / 256, Q / 256), 512, 0, stream>>>(M8, A8, P8, adj, wsum, counter, out);
}

// Round 11
// 193.886 us; speedup vs baseline: 2.5118x; 2.5118x over previous
//
#include <hip/hip_runtime.h>
#include <hip/hip_bf16.h>

// Problem sizes (fixed by reference setup_inputs):
//   B=16, N_LOG=512, N_PHYS(Q)=2048, E=2048
#define BATCH 16
#define NLOG 512
#define Q 2048
#define NEDGE 2048
#define M_TOT (BATCH * NLOG)   // 8192 global P rows
#define KB 2048                // K bytes per row (fp8) for gemm_a
#define GEMMB_BLOCKS 256       // 32 x 8

typedef float f32x2 __attribute__((ext_vector_type(2)));
typedef float f32x4 __attribute__((ext_vector_type(4)));
typedef int i32x4 __attribute__((ext_vector_type(4)));
typedef int i32x8 __attribute__((ext_vector_type(8)));

// float -> OCP e4m3 byte via HW packed-convert (RNE).
__device__ __forceinline__ unsigned char to_e4m3(float f) {
    int pk = __builtin_amdgcn_cvt_pk_fp8_f32(f, f, 0, false);
    return (unsigned char)(pk & 0xff);
}
// one OCP e4m3 byte -> f32 via HW packed convert (low element).
__device__ __forceinline__ float fp8_to_f32(unsigned char v) {
    f32x2 p = __builtin_amdgcn_cvt_pk_f32_fp8((int)v, false);
    return p[0];
}

// ---------------------------------------------------------------------------
// K1 (fused prep): blocks [0,8192) convert P fp32 -> P8 (e4m3, 8 elem/thr);
// blocks [8192,12288) build A8t[q][p] = (d_hw[p][q]==1) as e4m3 (1.0=0x38)
// via 32x32 LDS transpose; blocks [12288,16384) zero W32 (16 MB f32).
// Block 0 zeroes adj/wsum + the done counter.
__global__ __launch_bounds__(256) void prep(const float* __restrict__ P,
                                            unsigned char* __restrict__ P8,
                                            const int* __restrict__ d_hw,
                                            unsigned char* __restrict__ A8t,
                                            float* __restrict__ W32,
                                            float* __restrict__ adj,
                                            float* __restrict__ wsum,
                                            unsigned* __restrict__ counter) {
    int bid = blockIdx.x;
    if (bid == 0) {
        if (threadIdx.x == 0) *counter = 0u;
        if (threadIdx.x < BATCH) { adj[threadIdx.x] = 0.f; wsum[threadIdx.x] = 0.f; }
    }
    if (bid < 8192) {
        int i = (bid * 256 + threadIdx.x) * 8;
        float4 v0 = *(const float4*)(P + i);
        float4 v1 = *(const float4*)(P + i + 4);
        int lo = 0, hi = 0;
        lo = __builtin_amdgcn_cvt_pk_fp8_f32(v0.x, v0.y, lo, false);
        lo = __builtin_amdgcn_cvt_pk_fp8_f32(v0.z, v0.w, lo, true);
        hi = __builtin_amdgcn_cvt_pk_fp8_f32(v1.x, v1.y, hi, false);
        hi = __builtin_amdgcn_cvt_pk_fp8_f32(v1.z, v1.w, hi, true);
        int2 st; st.x = lo; st.y = hi;
        *(int2*)(P8 + i) = st;
    } else if (bid < 12288) {
        bid -= 8192;
        __shared__ unsigned char tile[32][33];
        int q0 = (bid & 63) * 32;
        int p0 = (bid >> 6) * 32;
        int tx = threadIdx.x & 31;
        int ty = threadIdx.x >> 5;  // 0..7
        for (int s = 0; s < 32; s += 8) {
            int p = p0 + ty + s;
            int v = d_hw[(size_t)p * Q + q0 + tx];
            tile[ty + s][tx] = (v == 1) ? 0x38 : 0x00;  // e4m3 1.0 / 0.0
        }
        __syncthreads();
        for (int s = 0; s < 32; s += 8) {
            A8t[(size_t)(q0 + ty + s) * Q + p0 + tx] = tile[tx][ty + s];
        }
    } else {
        // zero W32: 4096 blocks x 256 thr x 16 B = 16 MB.
        size_t off = ((size_t)(bid - 12288) * 256 + threadIdx.x) * 16;
        int4 z = {0, 0, 0, 0};
        *(int4*)((char*)W32 + off) = z;
    }
}

// ---------------------------------------------------------------------------
// K2 (w_build): scalar scatter W32[b][dst][src] += w_e (only 2048 f32
// atomicAdds per batch -- the 4-byte weight is scattered, NOT a 2 KB row;
// this kills R9's 341us latency-chain m_build). One block per batch also
// computes exact wsum[b].
__global__ __launch_bounds__(256) void w_build(const int* __restrict__ esrc,
                                               const int* __restrict__ edst,
                                               const float* __restrict__ ew,
                                               float* __restrict__ W32,
                                               float* __restrict__ wsum) {
    const int b = blockIdx.x;
    const int t = threadIdx.x;
    float wacc = 0.f;
    #pragma unroll
    for (int k = 0; k < NEDGE / 256; k++) {
        int e = b * NEDGE + k * 256 + t;
        int src = esrc[e];
        int dst = edst[e];
        float we = ew[e];
        atomicAdd(W32 + (size_t)b * NLOG * NLOG + dst * NLOG + src, we);
        wacc += we;
    }
    #pragma unroll
    for (int o = 32; o > 0; o >>= 1) wacc += __shfl_xor(wacc, o);
    __shared__ float rw[4];
    if ((t & 63) == 0) rw[t >> 6] = wacc;
    __syncthreads();
    if (t == 0) wsum[b] = rw[0] + rw[1] + rw[2] + rw[3];
}

// ---------------------------------------------------------------------------
// K3 (wquant): W32 f32 -> W8t e4m3 at 1/4 scale (headroom for colliding
// (dst,src) weight sums; un-scaled x4 in gemm_b's epilogue factor).
// 16 MB read, 4 MB write. GRID = 2048 EXACTLY: 2048 x 256 thr x 8 f32 =
// 4,194,304 = |W32|. (R10 BUG: launched 8192 -> wrote 16 MB into the 4 MB
// W8t, stomping adj/wsum/counter and past the workspace -> absmax 2.7e16.)
__global__ __launch_bounds__(256) void wquant(const float* __restrict__ W32,
                                              unsigned char* __restrict__ W8t) {
    int i = (blockIdx.x * 256 + threadIdx.x) * 8;
    float4 v0 = *(const float4*)(W32 + i);
    float4 v1 = *(const float4*)(W32 + i + 4);
    int lo = 0, hi = 0;
    lo = __builtin_amdgcn_cvt_pk_fp8_f32(v0.x * 0.25f, v0.y * 0.25f, lo, false);
    lo = __builtin_amdgcn_cvt_pk_fp8_f32(v0.z * 0.25f, v0.w * 0.25f, lo, true);
    hi = __builtin_amdgcn_cvt_pk_fp8_f32(v1.x * 0.25f, v1.y * 0.25f, hi, false);
    hi = __builtin_amdgcn_cvt_pk_fp8_f32(v1.z * 0.25f, v1.w * 0.25f, hi, true);
    int2 st; st.x = lo; st.y = hi;
    *(int2*)(W8t + i) = st;
}

// ---------------------------------------------------------------------------
// Shared 4-phase GEMM machinery (verified R7/R9): per K-tile, 4 sub-phases
// of {ds_read 1/4 frags || 2-3 staging loads for next K-tile -> RAW
// s_barrier -> setprio(1) -> 8 MFMAs -> setprio(0) -> raw barrier}; one
// vmcnt(0) at the K-tile boundary. 256x256 C-tile, 8 waves (2M x 4N),
// LDS 2x(32K+32K)=128KB, 1 block/CU. Chunk swizzle: rows are 128B = 32
// banks; phys chunk = logical ^ (row&7).
#define MF(af, bf, accv) __builtin_amdgcn_mfma_scale_f32_16x16x128_f8f6f4( \
    (af), (bf), (accv), 0, 0, 0, 127, 0, 127)

#define READ_FRAG(buf, rowbase) __extension__({                                \
    const int _b = ((rowbase) + lane16) << 7;                                  \
    i32x4 _lo = *(const i32x4*)((buf) + _b + c0);                              \
    i32x4 _hi = *(const i32x4*)((buf) + _b + c1);                              \
    __builtin_shufflevector(_lo, _hi, 0, 1, 2, 3, 4, 5, 6, 7); })

// staging: one call covers 64 rows x 128 B (512 thr x 16 B); thread t ->
// row t>>3, physical chunk t&7; source logical chunk = (t&7) ^ (row&7).
#define STAGE(srcp, stride, rowoff, dstbuf, c, kk0)                            \
    __builtin_amdgcn_global_load_lds(                                          \
        (const __attribute__((address_space(1))) void*)((srcp) +               \
            (size_t)((rowoff) + (c) * 64 + s_row) * (stride) + (kk0) + s_off), \
        (__attribute__((address_space(3))) void*)((dstbuf) + (c) * 8192 + t * 16), \
        16, 0, 0)

// K-tile body: phases 0-3 (st = stage-next flag, an/bn = next buffers).
#define KTILE_BODY(as, bs, DO_STAGE_A, DO_STAGE_B)                             \
    {                                                                          \
        i32x8 bf0 = READ_FRAG(bs, wc * 64 + 0);                                \
        i32x8 bf1 = READ_FRAG(bs, wc * 64 + 16);                               \
        i32x8 bf2 = READ_FRAG(bs, wc * 64 + 32);                               \
        i32x8 bf3 = READ_FRAG(bs, wc * 64 + 48);                               \
        i32x8 af0 = READ_FRAG(as, wr * 128 + 0);                               \
        i32x8 af1 = READ_FRAG(as, wr * 128 + 16);                              \
        if (st) { DO_STAGE_A(0); DO_STAGE_A(1); DO_STAGE_A(2); }               \
        __builtin_amdgcn_s_barrier();                                          \
        __builtin_amdgcn_s_setprio(1);                                         \
        acc[0][0] = MF(af0, bf0, acc[0][0]); acc[0][1] = MF(af0, bf1, acc[0][1]); \
        acc[0][2] = MF(af0, bf2, acc[0][2]); acc[0][3] = MF(af0, bf3, acc[0][3]); \
        acc[1][0] = MF(af1, bf0, acc[1][0]); acc[1][1] = MF(af1, bf1, acc[1][1]); \
        acc[1][2] = MF(af1, bf2, acc[1][2]); acc[1][3] = MF(af1, bf3, acc[1][3]); \
        __builtin_amdgcn_s_setprio(0);                                         \
        __builtin_amdgcn_s_barrier();                                          \
        i32x8 af2 = READ_FRAG(as, wr * 128 + 32);                              \
        i32x8 af3 = READ_FRAG(as, wr * 128 + 48);                              \
        if (st) { DO_STAGE_A(3); DO_STAGE_B(0); DO_STAGE_B(1); }               \
        __builtin_amdgcn_s_barrier();                                          \
        __builtin_amdgcn_s_setprio(1);                                         \
        acc[2][0] = MF(af2, bf0, acc[2][0]); acc[2][1] = MF(af2, bf1, acc[2][1]); \
        acc[2][2] = MF(af2, bf2, acc[2][2]); acc[2][3] = MF(af2, bf3, acc[2][3]); \
        acc[3][0] = MF(af3, bf0, acc[3][0]); acc[3][1] = MF(af3, bf1, acc[3][1]); \
        acc[3][2] = MF(af3, bf2, acc[3][2]); acc[3][3] = MF(af3, bf3, acc[3][3]); \
        __builtin_amdgcn_s_setprio(0);                                         \
        __builtin_amdgcn_s_barrier();                                          \
        i32x8 af4 = READ_FRAG(as, wr * 128 + 64);                              \
        i32x8 af5 = READ_FRAG(as, wr * 128 + 80);                              \
        if (st) { DO_STAGE_B(2); DO_STAGE_B(3); }                              \
        __builtin_amdgcn_s_barrier();                                          \
        __builtin_amdgcn_s_setprio(1);                                         \
        acc[4][0] = MF(af4, bf0, acc[4][0]); acc[4][1] = MF(af4, bf1, acc[4][1]); \
        acc[4][2] = MF(af4, bf2, acc[4][2]); acc[4][3] = MF(af4, bf3, acc[4][3]); \
        acc[5][0] = MF(af5, bf0, acc[5][0]); acc[5][1] = MF(af5, bf1, acc[5][1]); \
        acc[5][2] = MF(af5, bf2, acc[5][2]); acc[5][3] = MF(af5, bf3, acc[5][3]); \
        __builtin_amdgcn_s_setprio(0);                                         \
        __builtin_amdgcn_s_barrier();                                          \
        i32x8 af6 = READ_FRAG(as, wr * 128 + 96);                              \
        i32x8 af7 = READ_FRAG(as, wr * 128 + 112);                             \
        __builtin_amdgcn_s_barrier();                                          \
        __builtin_amdgcn_s_setprio(1);                                         \
        acc[6][0] = MF(af6, bf0, acc[6][0]); acc[6][1] = MF(af6, bf1, acc[6][1]); \
        acc[6][2] = MF(af6, bf2, acc[6][2]); acc[6][3] = MF(af6, bf3, acc[6][3]); \
        acc[7][0] = MF(af7, bf0, acc[7][0]); acc[7][1] = MF(af7, bf1, acc[7][1]); \
        acc[7][2] = MF(af7, bf2, acc[7][2]); acc[7][3] = MF(af7, bf3, acc[7][3]); \
        __builtin_amdgcn_s_setprio(0);                                         \
        asm volatile("s_waitcnt vmcnt(0)" ::: "memory");                       \
        __builtin_amdgcn_s_barrier();                                          \
    }

#define GEMM_COMMON_DECLS                                                      \
    const int t = threadIdx.x;                                                 \
    const int w = t >> 6;                                                      \
    const int wr = w >> 2, wc = w & 3;                                         \
    const int l = t & 63;                                                      \
    const int quad = l >> 4;                                                   \
    const int lane16 = l & 15;                                                 \
    const int s_row = t >> 3;                                                  \
    const int s_off = (((t & 7) ^ (s_row & 7)) << 4);                          \
    const int r7 = lane16 & 7;                                                 \
    const int c0 = ((2 * quad) ^ r7) << 4;                                     \
    const int c1 = ((2 * quad + 1) ^ r7) << 4;

// ---------------------------------------------------------------------------
// K4 (gemm_a): PA8t[q][gi] = e4m3( (1/256) * sum_p A8t[q,p] * P8[gi,p] ).
// Operand-swapped main GEMM -> produces PA^T with NO extra transposes.
// m = q (blockIdx.x, 8 tiles), n = global i (blockIdx.y, 32 tiles). K=2048.
__global__ __launch_bounds__(512, 2) void gemm_a(const unsigned char* __restrict__ At,
                                                 const unsigned char* __restrict__ Pp,
                                                 unsigned char* __restrict__ PA8t) {
    __shared__ unsigned char As[2][32768];
    __shared__ unsigned char Bs[2][32768];
    GEMM_COMMON_DECLS
    const int m0 = blockIdx.x * 256;   // q
    const int n0 = blockIdx.y * 256;   // global i

    f32x4 acc[8][4] = {};

#define SA_A(c) STAGE(At, Q, m0, an, c, kn)
#define SB_A(c) STAGE(Pp, Q, n0, bn, c, kn)
    {
        unsigned char* an = As[0]; unsigned char* bn = Bs[0];
        const int kn = 0;
        SA_A(0); SA_A(1); SA_A(2); SA_A(3);
        SB_A(0); SB_A(1); SB_A(2); SB_A(3);
    }
    __syncthreads();
    for (int kt = 0; kt < 16; ++kt) {
        const unsigned char* as = As[kt & 1];
        const unsigned char* bs = Bs[kt & 1];
        unsigned char* an = As[(kt + 1) & 1];
        unsigned char* bn = Bs[(kt + 1) & 1];
        const int kn = (kt + 1) * 128;
        const bool st = (kt < 15);
        KTILE_BODY(as, bs, SA_A, SB_A)
    }
#undef SA_A
#undef SB_A

    // epilogue: C/D layout: col=lane&15, row=quad*4+reg.
    #pragma unroll
    for (int i = 0; i < 8; i++) {
        #pragma unroll
        for (int j = 0; j < 4; j++) {
            #pragma unroll
            for (int r = 0; r < 4; r++) {
                int row = m0 + wr * 128 + i * 16 + quad * 4 + r;   // q
                int col = n0 + wc * 64 + j * 16 + lane16;          // global i
                PA8t[(size_t)row * M_TOT + col] = to_e4m3(acc[i][j][r] * (1.0f / 256.0f));
            }
        }
    }
}

// ---------------------------------------------------------------------------
// K5 (gemm_b, fused loss): N[gj,q] = sum_i W8t[gj,i] * PA8t[q, b*512+i],
// K=512 (4 K-tiles); epilogue: adj[b] += 1024 * sum N[gj,q]*P8[gj,q]
// (x4 undoes wquant scale, x256 undoes PA8t scale); counter-gated finalize.
// m = global j (blockIdx.x, 32 tiles; b = blockIdx.x>>1), n = q (8 tiles).
__global__ __launch_bounds__(512, 2) void gemm_b(const unsigned char* __restrict__ Wt,
                                                 const unsigned char* __restrict__ PAt,
                                                 const unsigned char* __restrict__ Pp,
                                                 float* __restrict__ adj,
                                                 const float* __restrict__ wsum,
                                                 unsigned* __restrict__ counter,
                                                 float* __restrict__ out) {
    __shared__ unsigned char As[2][32768];
    __shared__ unsigned char Bs[2][32768];
    __shared__ float rs[8];
    GEMM_COMMON_DECLS
    const int m0 = blockIdx.x * 256;        // global j
    const int n0 = blockIdx.y * 256;        // q
    const int b = blockIdx.x >> 1;
    const int kbase = b * NLOG;             // k-offset into PA8t columns

    f32x4 acc[8][4] = {};

#define SA_B(c) STAGE(Wt, NLOG, m0, an, c, kn)
#define SB_B(c) STAGE(PAt + kbase, M_TOT, n0, bn, c, kn)
    {
        unsigned char* an = As[0]; unsigned char* bn = Bs[0];
        const int kn = 0;
        SA_B(0); SA_B(1); SA_B(2); SA_B(3);
        SB_B(0); SB_B(1); SB_B(2); SB_B(3);
    }
    __syncthreads();
    for (int kt = 0; kt < 4; ++kt) {
        const unsigned char* as = As[kt & 1];
        const unsigned char* bs = Bs[kt & 1];
        unsigned char* an = As[(kt + 1) & 1];
        unsigned char* bn = Bs[(kt + 1) & 1];
        const int kn = (kt + 1) * 128;
        const bool st = (kt < 3);
        KTILE_BODY(as, bs, SA_B, SB_B)
    }
#undef SA_B
#undef SB_B

    // epilogue: s = sum over tile of N[row,col] * P8[row,col].
    float s = 0.f;
    #pragma unroll
    for (int i = 0; i < 8; i++) {
        #pragma unroll
        for (int j = 0; j < 4; j++) {
            #pragma unroll
            for (int r = 0; r < 4; r++) {
                int row = m0 + wr * 128 + i * 16 + quad * 4 + r;   // global j
                int col = n0 + wc * 64 + j * 16 + lane16;          // q
                s += acc[i][j][r] * fp8_to_f32(Pp[(size_t)row * Q + col]);
            }
        }
    }
    #pragma unroll
    for (int o = 32; o > 0; o >>= 1) s += __shfl_xor(s, o);
    if (l == 0) rs[w] = s;
    __syncthreads();

    if (t == 0) {
        float a = 0.f;
        #pragma unroll
        for (int i = 0; i < 8; i++) a += rs[i];
        atomicAdd(&adj[b], a * 1024.0f);
        __threadfence();
        if (atomicAdd(counter, 1u) == GEMMB_BLOCKS - 1) {
            __threadfence();
            float sm = 0.f;
            #pragma unroll
            for (int bb = 0; bb < BATCH; bb++) {
                float av = atomicAdd(&adj[bb], 0.0f);   // device-scope read
                float wv = atomicAdd((float*)&wsum[bb], 0.0f);
                sm += av / fmaxf(wv, 1e-8f);
            }
            out[0] = -sm / (float)BATCH;
        }
    }
}

// ---------------------------------------------------------------------------
extern "C" void kernel_launch(void* const* d_in, const int* in_sizes, int n_in,
                              void* d_out, int out_size, void* d_ws, size_t ws_size,
                              hipStream_t stream) {
    const float* P    = (const float*)d_in[0];
    const int* d_hw   = (const int*)d_in[1];
    const int* esrc   = (const int*)d_in[2];
    const int* edst   = (const int*)d_in[3];
    const float* ew   = (const float*)d_in[4];
    float* out        = (float*)d_out;

    char* ws = (char*)d_ws;
    // workspace layout (bytes), total ~58.7 MB:
    //   P8   : e4m3 [8192][2048]  = 16,777,216   [0, 16.8M)
    //   A8t  : e4m3 [2048][2048]  =  4,194,304   [16.8M, 21.0M)
    //   PA8t : e4m3 [2048][8192]  = 16,777,216   [21.0M, 37.7M)  (PA^T/256)
    //   W32  : f32  [16][512][512]= 16,777,216   [37.7M, 54.5M)
    //   W8t  : e4m3 [8192][512]   =  4,194,304   [54.5M, 58.7M)  (W^T/4)
    //   adj/wsum/counter at 58.7M
    unsigned char* P8   = (unsigned char*)ws;
    unsigned char* A8t  = (unsigned char*)(ws + 16777216);
    unsigned char* PA8t = (unsigned char*)(ws + 20971520);
    float* W32          = (float*)(ws + 37748736);
    unsigned char* W8t  = (unsigned char*)(ws + 54525952);
    float* adj          = (float*)(ws + 58720256);
    float* wsum         = (float*)(ws + 58720256 + 64);
    unsigned* counter   = (unsigned*)(ws + 58720256 + 128);

    prep<<<16384, 256, 0, stream>>>(P, P8, d_hw, A8t, W32, adj, wsum, counter);
    w_build<<<BATCH, 256, 0, stream>>>(esrc, edst, ew, W32, wsum);
    wquant<<<2048, 256, 0, stream>>>(W32, W8t);   // 2048*256*8 = |W32| exactly
    gemm_a<<<dim3(Q / 256, M_TOT / 256), 512, 0, stream>>>(A8t, P8, PA8t);
    gemm_b<<<dim3(M_TOT / 256, Q / 256), 512, 0, stream>>>(W8t, PA8t, P8, adj, wsum, counter, out);
}